// Round 7
// baseline (336.811 us; speedup 1.0000x reference)
//
#include <hip/hip_runtime.h>
#include <stdint.h>

// Problem constants
#define S_LEN 2048
#define DIM   2048
#define NH    16
#define NKV   4
#define HD    128
#define QKV_E 3072   // (16 + 2*4) * 128

typedef unsigned short u16;
typedef __attribute__((ext_vector_type(8))) short short8;    // 8 x bf16 MFMA operand
typedef __attribute__((ext_vector_type(4))) float floatx4;   // 16x16 accumulator
typedef __attribute__((ext_vector_type(16))) float floatx16; // 32x32 accumulator

__device__ __forceinline__ u16 f2bf(float f) {
  unsigned u = __float_as_uint(f);
  u = u + 0x7fffu + ((u >> 16) & 1u);   // RNE
  return (u16)(u >> 16);
}
__device__ __forceinline__ float bf2f(u16 b) {
  return __uint_as_float(((unsigned)b) << 16);
}

__device__ __forceinline__ void gload16(const void* g, void* l) {
  __builtin_amdgcn_global_load_lds((const __attribute__((address_space(1))) void*)g,
                                   (__attribute__((address_space(3))) void*)l, 16, 0, 0);
}

#define FENCE() asm volatile("" ::: "memory")
#define BARF()  do { FENCE(); __builtin_amdgcn_s_barrier(); FENCE(); } while (0)

// ---------------- fused f32 -> bf16 casts (x, wqkv, wo) ----------------
__global__ __launch_bounds__(256) void cast3(const float* __restrict__ x,
                                             const float* __restrict__ wq,
                                             const float* __restrict__ wo,
                                             u16* __restrict__ xb,
                                             u16* __restrict__ wqb,
                                             u16* __restrict__ wob) {
  const int n1 = 2097152;              // 4096*2048/4
  const int n2 = n1 + 1572864;         // + 3072*2048/4
  const int n3 = n2 + 1048576;         // + 2048*2048/4
  int i = blockIdx.x * 256 + threadIdx.x;
  for (; i < n3; i += gridDim.x * 256) {
    const float* s; u16* d; int j;
    if (i < n1)      { s = x;  d = xb;  j = i; }
    else if (i < n2) { s = wq; d = wqb; j = i - n1; }
    else             { s = wo; d = wob; j = i - n2; }
    float4 v = ((const float4*)s)[j];
    ushort4 o;
    o.x = f2bf(v.x); o.y = f2bf(v.y); o.z = f2bf(v.z); o.w = f2bf(v.w);
    ((ushort4*)d)[j] = o;
  }
}

// ---------------- 8-phase bf16 GEMM, C = A * B^T, BMT x 256 tile ----------
// (unchanged from round 6 — verified)
template <int OBF16, int BMT>
__global__ __launch_bounds__(512, 2) void gemm256(const u16* __restrict__ A,
                                                  const u16* __restrict__ B,
                                                  float* __restrict__ C,
                                                  u16* __restrict__ Cb,
                                                  int M, int N, int K) {
  extern __shared__ char sm[];   // [A: 2*ABUF][B: 2*32KB]
  constexpr int ABUF = BMT * 128;     // bytes per A k-tile buffer
  constexpr int BOFF = 2 * ABUF;
  const int tid  = threadIdx.x;
  const int wid  = tid >> 6;
  const int lane = tid & 63;
  const int gg   = lane >> 4;
  const int c16  = lane & 15;
  const int wm   = wid >> 2;       // 0..1
  const int wn   = wid & 3;        // 0..3
  const int m0 = blockIdx.y * BMT;
  const int n0 = blockIdx.x * 256;
  const int NT = K >> 6;

  floatx4 acc[(BMT == 256) ? 8 : 4][4] = {};
  short8 af[4][2], bfv0[2][2], bfv1[2][2];

  auto stageA = [&](int kt, int h) {
#pragma unroll
    for (int i = 0; i < 2; ++i) {
      int lr = wid * 16 + i * 8 + (lane >> 3);
      int sb = (lane & 7) * 16;
      int grow = (BMT == 256) ? ((lr >> 6) * 128 + h * 64 + (lr & 63)) : lr;
      const char* g = (const char*)(A + (size_t)(m0 + grow) * K + (size_t)kt * 64)
                      + (sb ^ ((lr & 7) << 4));
      gload16(g, sm + (kt & 1) * ABUF + h * 16384 + (wid * 16 + i * 8) * 128);
    }
  };
  auto stageB = [&](int kt, int g) {
#pragma unroll
    for (int i = 0; i < 2; ++i) {
      int lr = wid * 16 + i * 8 + (lane >> 3);
      int sb = (lane & 7) * 16;
      int grow = (lr >> 5) * 64 + g * 32 + (lr & 31);
      const char* gp = (const char*)(B + (size_t)(n0 + grow) * K + (size_t)kt * 64)
                       + (sb ^ ((lr & 7) << 4));
      gload16(gp, sm + BOFF + (kt & 1) * 32768 + g * 16384 + (wid * 16 + i * 8) * 128);
    }
  };
  auto loadA = [&](int buf, int mh) {
    const char* Ab = sm + buf * ABUF + mh * 16384;
#pragma unroll
    for (int mm = 0; mm < 4; ++mm) {
      int lr = wm * 64 + mm * 16 + c16;
#pragma unroll
      for (int ks = 0; ks < 2; ++ks)
        af[mm][ks] = *(const short8*)(Ab + lr * 128 +
                        ((ks * 64 + gg * 16) ^ ((lr & 7) << 4)));
    }
  };
  auto loadB = [&](int buf, int ng, short8 (&bfv)[2][2]) {
    const char* Bb = sm + BOFF + buf * 32768 + ng * 16384;
#pragma unroll
    for (int nn = 0; nn < 2; ++nn) {
      int lr = wn * 32 + nn * 16 + c16;
#pragma unroll
      for (int ks = 0; ks < 2; ++ks)
        bfv[nn][ks] = *(const short8*)(Bb + lr * 128 +
                        ((ks * 64 + gg * 16) ^ ((lr & 7) << 4)));
    }
  };
  auto mfma16 = [&](int mh, int ng, short8 (&bfv)[2][2]) {
    __builtin_amdgcn_s_setprio(1);
#pragma unroll
    for (int mm = 0; mm < 4; ++mm)
#pragma unroll
      for (int nn = 0; nn < 2; ++nn) {
        int mf = (BMT == 256) ? (mh * 4 + mm) : mm;
        acc[mf][ng * 2 + nn] = __builtin_amdgcn_mfma_f32_16x16x32_bf16(
            af[mm][0], bfv[nn][0], acc[mf][ng * 2 + nn], 0, 0, 0);
        acc[mf][ng * 2 + nn] = __builtin_amdgcn_mfma_f32_16x16x32_bf16(
            af[mm][1], bfv[nn][1], acc[mf][ng * 2 + nn], 0, 0, 0);
      }
    __builtin_amdgcn_s_setprio(0);
    FENCE();
  };

  if (BMT == 256) {
    stageA(0, 0); stageB(0, 0); stageA(0, 1); stageB(0, 1);
    stageA(1, 0); stageB(1, 0);
    asm volatile("s_waitcnt vmcnt(4)" ::: "memory");
    BARF();
    for (int t = 0; t < NT; ++t) {
      const int buf = t & 1;
      loadA(buf, 0); loadB(buf, 0, bfv0);
      if (t + 1 < NT) stageA(t + 1, 1);
      BARF(); mfma16(0, 0, bfv0); BARF();
      loadB(buf, 1, bfv1);
      if (t + 1 < NT) stageB(t + 1, 1);
      BARF(); mfma16(0, 1, bfv1); BARF();
      loadA(buf, 1);
      if (t + 2 < NT) stageA(t + 2, 0);
      BARF(); mfma16(1, 0, bfv0); BARF();
      if (t + 2 < NT) stageB(t + 2, 0);
      BARF(); mfma16(1, 1, bfv1);
      if (t + 2 < NT) asm volatile("s_waitcnt vmcnt(4)" ::: "memory");
      else            asm volatile("s_waitcnt vmcnt(0)" ::: "memory");
      BARF();
    }
  } else {
    stageA(0, 0); stageB(0, 0); stageB(0, 1);
    asm volatile("s_waitcnt vmcnt(0)" ::: "memory");
    BARF();
    for (int t = 0; t < NT; ++t) {
      const int buf = t & 1;
      loadA(buf, 0); loadB(buf, 0, bfv0);
      if (t + 1 < NT) { stageA(t + 1, 0); stageB(t + 1, 0); }
      BARF(); mfma16(0, 0, bfv0);
      if (t + 1 < NT) asm volatile("s_waitcnt vmcnt(4)" ::: "memory");
      else            asm volatile("s_waitcnt vmcnt(0)" ::: "memory");
      BARF();
      loadB(buf, 1, bfv1);
      if (t + 1 < NT) stageB(t + 1, 1);
      BARF(); mfma16(0, 1, bfv1);
      if (t + 1 < NT) asm volatile("s_waitcnt vmcnt(2)" ::: "memory");
      BARF();
    }
  }

  constexpr int MFT = (BMT == 256) ? 8 : 4;
  constexpr int WROW = (BMT == 256) ? 128 : 64;
#pragma unroll
  for (int mf = 0; mf < MFT; ++mf)
#pragma unroll
    for (int nf = 0; nf < 4; ++nf) {
      int row = m0 + wm * WROW + mf * 16 + gg * 4;
      int col = n0 + wn * 64 + nf * 16 + c16;
      if (OBF16) {
        u16* cp = Cb + (size_t)row * N + col;
#pragma unroll
        for (int r = 0; r < 4; ++r) cp[(size_t)r * N] = f2bf(acc[mf][nf][r]);
      } else {
        float* cp = C + (size_t)row * N + col;
#pragma unroll
        for (int r = 0; r < 4; ++r) cp[(size_t)r * N] = acc[mf][nf][r];
      }
    }
}

// ---------------- RMSNorm + RoPE + split/cast ----------------
__global__ __launch_bounds__(256) void normrope(const u16* __restrict__ qkv,
                                                const float* __restrict__ freqs,
                                                const float* __restrict__ qw,
                                                const float* __restrict__ kw,
                                                u16* __restrict__ Qb,
                                                u16* __restrict__ Kb,
                                                u16* __restrict__ Vt) {
  int row  = blockIdx.x * 4 + (threadIdx.x >> 6);   // over B*S*24
  int lane = threadIdx.x & 63;
  int bs = row / 24, h = row % 24;
  int b = bs >> 11, s = bs & (S_LEN - 1);
  const u16* src = qkv + (size_t)bs * QKV_E + h * HD;
  ushort2 xr = *(const ushort2*)(src + 2 * lane);
  float x0 = bf2f(xr.x), x1 = bf2f(xr.y);

  float ss = x0 * x0 + x1 * x1;
#pragma unroll
  for (int off = 32; off; off >>= 1) ss += __shfl_xor(ss, off);
  float rn = rsqrtf(ss * (1.0f / 128.0f) + 1e-5f);

  const float scale = 0.08838834764831845f;  // 1/sqrt(128), folded into Q
  if (h < 20) {
    const float* w = (h < 16) ? qw : kw;
    float y0 = x0 * rn * w[2 * lane];
    float y1 = x1 * rn * w[2 * lane + 1];
    float2 f = *(const float2*)(freqs + (size_t)s * 128 + 2 * lane);  // cos, sin
    float r0 = y0 * f.x - y1 * f.y;
    float r1 = y1 * f.x + y0 * f.y;
    ushort2 o;
    if (h < 16) { o.x = f2bf(r0 * scale); o.y = f2bf(r1 * scale); }
    else        { o.x = f2bf(r0);         o.y = f2bf(r1); }
    u16* dst = (h < 16) ? (Qb + ((size_t)(b * NH  + h)      * S_LEN + s) * HD)
                        : (Kb + ((size_t)(b * NKV + h - 16) * S_LEN + s) * HD);
    *(ushort2*)(dst + 2 * lane) = o;
  } else {
    u16* dst = Vt + (size_t)(b * NKV + (h - 20)) * HD * S_LEN;
    dst[(size_t)(2 * lane)     * S_LEN + s] = f2bf(x0);
    dst[(size_t)(2 * lane + 1) * S_LEN + s] = f2bf(x1);
  }
}

// ---------------- MFMA flash attention, 32x32x16, fixed-base softmax ------
// Block: 4 waves x 32 q-rows = 128 q-rows; pairing {bx, 15-bx} -> 34 uniform
// K-steps (KT=64). Double-buffered K/V staging, counted vmcnt(8).
// Swapped QK^T (mfma(K,Q) -> S^T with col=lane&31=q); P redistributed fully
// in-register via cvt_pk_bf16 + permlane32_swap; L via ones-MFMA (same
// layout as O). Ks rows 256B / VtS rows 128B, row-XOR swizzle ((r&7)<<4).
#define KT 64

__global__ __launch_bounds__(256, 1) void attn_mfma(const u16* __restrict__ Qb,
                                                    const u16* __restrict__ Kb,
                                                    const u16* __restrict__ Vt,
                                                    u16* __restrict__ Yb) {
  __shared__ u16 Ks[2][KT * HD];       // 2 x 16 KB
  __shared__ u16 VtS[2][HD * KT];      // 2 x 16 KB

  const int wid  = threadIdx.x >> 6;
  const int lane = threadIdx.x & 63;
  const int gg   = lane >> 4;          // staging
  const int c16  = lane & 15;          // staging
  const int c31  = lane & 31;
  const int hi   = lane >> 5;
  const int b = blockIdx.z, h = blockIdx.y, bx = blockIdx.x;
  const int hv = h >> 2;

  const u16* Qp = Qb + ((size_t)(b * NH  + h)  * S_LEN) * HD;
  const u16* Kp = Kb + ((size_t)(b * NKV + hv) * S_LEN) * HD;
  const u16* Vp = Vt + ((size_t)(b * NKV + hv) * HD) * S_LEN;

  short8 onesf;
#pragma unroll
  for (int i = 0; i < 8; ++i) onesf[i] = (short)0x3F80;  // bf16 1.0

  auto stageK = [&](int k0, int sel) {
#pragma unroll
    for (int i = 0; i < 4; ++i) {
      int rbase = wid * 16 + i * 4;
      int r = rbase + gg;
      int cb = c16 * 16;
      gload16((const char*)Kp + (size_t)(k0 + r) * 256 + (cb ^ ((r & 7) << 4)),
              (char*)Ks[sel] + rbase * 256);
    }
  };
  auto stageV = [&](int k0, int sel) {
#pragma unroll
    for (int i = 0; i < 4; ++i) {
      int rbase = wid * 32 + i * 8;
      int r = rbase + (lane >> 3);
      int cb = (lane & 7) * 16;
      gload16((const char*)Vp + (size_t)r * (S_LEN * 2) + (size_t)k0 * 2 + (cb ^ ((r & 7) << 4)),
              (char*)VtS[sel] + rbase * 128);
    }
  };

  for (int pass = 0; pass < 2; ++pass) {
    const int qt  = pass ? (15 - bx) : bx;
    const int q0  = qt * 128;
    const int q0w = q0 + wid * 32;     // wave's first q row
    const int q   = q0w + c31;         // this lane's q (as S^T column)
    const int nst = 2 * qt + 2;

    // Q fragments (B operand): lane holds Q[q][ds*16 + hi*8 .. +7]
    short8 qf[8];
    {
      const u16* qrow = Qp + (size_t)q * HD + hi * 8;
#pragma unroll
      for (int ds = 0; ds < 8; ++ds) qf[ds] = *(const short8*)(qrow + ds * 16);
    }

    floatx16 Oacc[4] = {};
    floatx16 Lacc = {};

    stageK(0, 0); stageV(0, 0);
    for (int t = 0; t < nst; ++t) {
      const int k0 = t * KT;
      if (t + 1 < nst) { stageK(k0 + KT, (t + 1) & 1); stageV(k0 + KT, (t + 1) & 1); }
      if (t + 1 < nst) asm volatile("s_waitcnt vmcnt(8)" ::: "memory");
      else             asm volatile("s_waitcnt vmcnt(0)" ::: "memory");
      BARF();

      if (k0 <= q0w + 31) {
        const char* KsB = (const char*)Ks[t & 1];
        const char* VtB = (const char*)VtS[t & 1];
        const bool upper = (k0 + 32 <= q0w + 31);   // keys k0+32..k0+63 needed
        const bool fullT = (k0 + 63 <= q0w);        // no masking anywhere

        // halves: kh = 0 -> keys k0..k0+31, kh = 1 -> k0+32..k0+63
#pragma unroll
        for (int kh = 0; kh < 2; ++kh) {
          if (kh == 1 && !upper) break;
          // ---- QK^T: st = S^T 32k x 32q
          floatx16 st = {};
          const int krow = kh * 32 + c31;
          const char* kbase = KsB + krow * 256;
          const int swz = (krow & 7) << 4;
#pragma unroll
          for (int ds = 0; ds < 8; ++ds) {
            short8 kf = *(const short8*)(kbase + ((ds * 32 + hi * 16) ^ swz));
            st = __builtin_amdgcn_mfma_f32_32x32x16_bf16(kf, qf[ds], st, 0, 0, 0);
          }
          // ---- p = exp(s), mask; lane's k = kb + (r&3)+8*(r>>2)+4*hi
          const int kb = k0 + kh * 32;
          float p[16];
          if (fullT) {
#pragma unroll
            for (int r = 0; r < 16; ++r) p[r] = __expf(st[r]);
          } else {
#pragma unroll
            for (int r = 0; r < 16; ++r) {
              int k = kb + (r & 3) + 8 * (r >> 2) + 4 * hi;
              p[r] = (k <= q) ? __expf(st[r]) : 0.f;
            }
          }
          // ---- pack to bf16 pairs + permlane32_swap -> PV A-fragments
          unsigned w[8];
#pragma unroll
          for (int m = 0; m < 8; ++m)
            asm("v_cvt_pk_bf16_f32 %0, %1, %2" : "=v"(w[m]) : "v"(p[2*m]), "v"(p[2*m+1]));
          asm volatile("v_permlane32_swap_b32 %0, %1" : "+v"(w[0]), "+v"(w[2]));
          asm volatile("v_permlane32_swap_b32 %0, %1" : "+v"(w[1]), "+v"(w[3]));
          asm volatile("v_permlane32_swap_b32 %0, %1" : "+v"(w[4]), "+v"(w[6]));
          asm volatile("v_permlane32_swap_b32 %0, %1" : "+v"(w[5]), "+v"(w[7]));
          short8 pa0, pa1;
          {
            unsigned u0[4] = {w[0], w[1], w[2], w[3]};
            unsigned u1[4] = {w[4], w[5], w[6], w[7]};
            pa0 = *(const short8*)u0;
            pa1 = *(const short8*)u1;
          }
          // ---- L row-sums (same C/D layout as Oacc)
          Lacc = __builtin_amdgcn_mfma_f32_32x32x16_bf16(pa0, onesf, Lacc, 0, 0, 0);
          Lacc = __builtin_amdgcn_mfma_f32_32x32x16_bf16(pa1, onesf, Lacc, 0, 0, 0);
          // ---- PV: O[q][d] += P[q][k] V[k][d]
#pragma unroll
          for (int dt = 0; dt < 4; ++dt) {
            const int vr = dt * 32 + c31;
            const char* vbase = VtB + vr * 128;
            const int swzv = (vr & 7) << 4;
            short8 vf0 = *(const short8*)(vbase + (((kh * 2 + 0) * 32 + hi * 16) ^ swzv));
            short8 vf1 = *(const short8*)(vbase + (((kh * 2 + 1) * 32 + hi * 16) ^ swzv));
            Oacc[dt] = __builtin_amdgcn_mfma_f32_32x32x16_bf16(pa0, vf0, Oacc[dt], 0, 0, 0);
            Oacc[dt] = __builtin_amdgcn_mfma_f32_32x32x16_bf16(pa1, vf1, Oacc[dt], 0, 0, 0);
          }
        }
      }
      BARF();
    }

    // ---- epilogue: O / L -> Yb [b][s][h*128+d]; row q = (r&3)+8*(r>>2)+4*hi
    float linv[16];
#pragma unroll
    for (int r = 0; r < 16; ++r) linv[r] = 1.0f / Lacc[r];
#pragma unroll
    for (int dt = 0; dt < 4; ++dt) {
      const int d = dt * 32 + c31;
#pragma unroll
      for (int r = 0; r < 16; ++r) {
        int qg = q0w + (r & 3) + 8 * (r >> 2) + 4 * hi;
        Yb[((size_t)(b * S_LEN + qg)) * DIM + h * HD + d] = f2bf(Oacc[dt][r] * linv[r]);
      }
    }
  }
}

// ---------------- launch ----------------
extern "C" void kernel_launch(void* const* d_in, const int* in_sizes, int n_in,
                              void* d_out, int out_size, void* d_ws, size_t ws_size,
                              hipStream_t stream) {
  const float* x     = (const float*)d_in[0];
  const float* freqs = (const float*)d_in[1];
  const float* wqkv  = (const float*)d_in[3];
  const float* wo    = (const float*)d_in[4];
  const float* qw    = (const float*)d_in[5];
  const float* kw    = (const float*)d_in[6];
  float* out = (float*)d_out;
  char* ws = (char*)d_ws;

  const int M = 2 * S_LEN;  // 4096 rows (B*S)

  u16* xb    = (u16*)(ws);                 // 16 MB
  u16* wqkvb = (u16*)(ws + 16777216);      // 12 MB
  u16* wob   = (u16*)(ws + 29360128);      //  8 MB
  u16* qkvb  = (u16*)(ws + 37748736);      // 24 MB (bf16 GEMM output)
  u16* Qb    = (u16*)(ws + 62914560);      // 16 MB
  u16* Kb    = (u16*)(ws + 79691776);      //  4 MB
  u16* Vt    = (u16*)(ws + 83886080);      //  4 MB
  u16* Yb    = (u16*)(ws + 88080384);      // 16 MB  (end 100 MB)

  hipFuncSetAttribute((const void*)gemm256<1, 256>,
                      hipFuncAttributeMaxDynamicSharedMemorySize, 131072);
  hipFuncSetAttribute((const void*)gemm256<0, 128>,
                      hipFuncAttributeMaxDynamicSharedMemorySize, 98304);

  cast3<<<2048, 256, 0, stream>>>(x, wqkv, wo, xb, wqkvb, wob);

  gemm256<1, 256><<<dim3(QKV_E / 256, M / 256), 512, 131072, stream>>>(
      xb, wqkvb, nullptr, qkvb, M, QKV_E, DIM);

  normrope<<<(M * 24) / 4, 256, 0, stream>>>(qkvb, freqs, qw, kw, Qb, Kb, Vt);

  attn_mfma<<<dim3(8, NH, 2), 256, 0, stream>>>(Qb, Kb, Vt, Yb);

  gemm256<0, 128><<<dim3(DIM / 256, M / 128), 512, 98304, stream>>>(
      Yb, wob, out, nullptr, M, DIM, DIM);
}

// Round 8
// 333.647 us; speedup vs baseline: 1.0095x; 1.0095x over previous
//
#include <hip/hip_runtime.h>
#include <stdint.h>

// Problem constants
#define S_LEN 2048
#define DIM   2048
#define NH    16
#define NKV   4
#define HD    128
#define QKV_E 3072   // (16 + 2*4) * 128

typedef unsigned short u16;
typedef __attribute__((ext_vector_type(8))) short short8;    // 8 x bf16 MFMA operand
typedef __attribute__((ext_vector_type(4))) float floatx4;   // 16x16 accumulator
typedef __attribute__((ext_vector_type(16))) float floatx16; // 32x32 accumulator

__device__ __forceinline__ u16 f2bf(float f) {
  unsigned u = __float_as_uint(f);
  u = u + 0x7fffu + ((u >> 16) & 1u);   // RNE
  return (u16)(u >> 16);
}
__device__ __forceinline__ float bf2f(u16 b) {
  return __uint_as_float(((unsigned)b) << 16);
}

__device__ __forceinline__ void gload16(const void* g, void* l) {
  __builtin_amdgcn_global_load_lds((const __attribute__((address_space(1))) void*)g,
                                   (__attribute__((address_space(3))) void*)l, 16, 0, 0);
}

#define FENCE() asm volatile("" ::: "memory")
#define BARF()  do { FENCE(); __builtin_amdgcn_s_barrier(); FENCE(); } while (0)

// ---------------- fused f32 -> bf16 casts (x, wqkv, wo) ----------------
__global__ __launch_bounds__(256) void cast3(const float* __restrict__ x,
                                             const float* __restrict__ wq,
                                             const float* __restrict__ wo,
                                             u16* __restrict__ xb,
                                             u16* __restrict__ wqb,
                                             u16* __restrict__ wob) {
  const int n1 = 2097152;              // 4096*2048/4
  const int n2 = n1 + 1572864;         // + 3072*2048/4
  const int n3 = n2 + 1048576;         // + 2048*2048/4
  int i = blockIdx.x * 256 + threadIdx.x;
  for (; i < n3; i += gridDim.x * 256) {
    const float* s; u16* d; int j;
    if (i < n1)      { s = x;  d = xb;  j = i; }
    else if (i < n2) { s = wq; d = wqb; j = i - n1; }
    else             { s = wo; d = wob; j = i - n2; }
    float4 v = ((const float4*)s)[j];
    ushort4 o;
    o.x = f2bf(v.x); o.y = f2bf(v.y); o.z = f2bf(v.z); o.w = f2bf(v.w);
    ((ushort4*)d)[j] = o;
  }
}

// ---------------- 8-phase bf16 GEMM, C = A * B^T, BMT x 256 tile ----------
// (unchanged — verified round 6)
template <int OBF16, int BMT>
__global__ __launch_bounds__(512, 2) void gemm256(const u16* __restrict__ A,
                                                  const u16* __restrict__ B,
                                                  float* __restrict__ C,
                                                  u16* __restrict__ Cb,
                                                  int M, int N, int K) {
  extern __shared__ char sm[];   // [A: 2*ABUF][B: 2*32KB]
  constexpr int ABUF = BMT * 128;     // bytes per A k-tile buffer
  constexpr int BOFF = 2 * ABUF;
  const int tid  = threadIdx.x;
  const int wid  = tid >> 6;
  const int lane = tid & 63;
  const int gg   = lane >> 4;
  const int c16  = lane & 15;
  const int wm   = wid >> 2;       // 0..1
  const int wn   = wid & 3;        // 0..3
  const int m0 = blockIdx.y * BMT;
  const int n0 = blockIdx.x * 256;
  const int NT = K >> 6;

  floatx4 acc[(BMT == 256) ? 8 : 4][4] = {};
  short8 af[4][2], bfv0[2][2], bfv1[2][2];

  auto stageA = [&](int kt, int h) {
#pragma unroll
    for (int i = 0; i < 2; ++i) {
      int lr = wid * 16 + i * 8 + (lane >> 3);
      int sb = (lane & 7) * 16;
      int grow = (BMT == 256) ? ((lr >> 6) * 128 + h * 64 + (lr & 63)) : lr;
      const char* g = (const char*)(A + (size_t)(m0 + grow) * K + (size_t)kt * 64)
                      + (sb ^ ((lr & 7) << 4));
      gload16(g, sm + (kt & 1) * ABUF + h * 16384 + (wid * 16 + i * 8) * 128);
    }
  };
  auto stageB = [&](int kt, int g) {
#pragma unroll
    for (int i = 0; i < 2; ++i) {
      int lr = wid * 16 + i * 8 + (lane >> 3);
      int sb = (lane & 7) * 16;
      int grow = (lr >> 5) * 64 + g * 32 + (lr & 31);
      const char* gp = (const char*)(B + (size_t)(n0 + grow) * K + (size_t)kt * 64)
                       + (sb ^ ((lr & 7) << 4));
      gload16(gp, sm + BOFF + (kt & 1) * 32768 + g * 16384 + (wid * 16 + i * 8) * 128);
    }
  };
  auto loadA = [&](int buf, int mh) {
    const char* Ab = sm + buf * ABUF + mh * 16384;
#pragma unroll
    for (int mm = 0; mm < 4; ++mm) {
      int lr = wm * 64 + mm * 16 + c16;
#pragma unroll
      for (int ks = 0; ks < 2; ++ks)
        af[mm][ks] = *(const short8*)(Ab + lr * 128 +
                        ((ks * 64 + gg * 16) ^ ((lr & 7) << 4)));
    }
  };
  auto loadB = [&](int buf, int ng, short8 (&bfv)[2][2]) {
    const char* Bb = sm + BOFF + buf * 32768 + ng * 16384;
#pragma unroll
    for (int nn = 0; nn < 2; ++nn) {
      int lr = wn * 32 + nn * 16 + c16;
#pragma unroll
      for (int ks = 0; ks < 2; ++ks)
        bfv[nn][ks] = *(const short8*)(Bb + lr * 128 +
                        ((ks * 64 + gg * 16) ^ ((lr & 7) << 4)));
    }
  };
  auto mfma16 = [&](int mh, int ng, short8 (&bfv)[2][2]) {
    __builtin_amdgcn_s_setprio(1);
#pragma unroll
    for (int mm = 0; mm < 4; ++mm)
#pragma unroll
      for (int nn = 0; nn < 2; ++nn) {
        int mf = (BMT == 256) ? (mh * 4 + mm) : mm;
        acc[mf][ng * 2 + nn] = __builtin_amdgcn_mfma_f32_16x16x32_bf16(
            af[mm][0], bfv[nn][0], acc[mf][ng * 2 + nn], 0, 0, 0);
        acc[mf][ng * 2 + nn] = __builtin_amdgcn_mfma_f32_16x16x32_bf16(
            af[mm][1], bfv[nn][1], acc[mf][ng * 2 + nn], 0, 0, 0);
      }
    __builtin_amdgcn_s_setprio(0);
    FENCE();
  };

  if (BMT == 256) {
    stageA(0, 0); stageB(0, 0); stageA(0, 1); stageB(0, 1);
    stageA(1, 0); stageB(1, 0);
    asm volatile("s_waitcnt vmcnt(4)" ::: "memory");
    BARF();
    for (int t = 0; t < NT; ++t) {
      const int buf = t & 1;
      loadA(buf, 0); loadB(buf, 0, bfv0);
      if (t + 1 < NT) stageA(t + 1, 1);
      BARF(); mfma16(0, 0, bfv0); BARF();
      loadB(buf, 1, bfv1);
      if (t + 1 < NT) stageB(t + 1, 1);
      BARF(); mfma16(0, 1, bfv1); BARF();
      loadA(buf, 1);
      if (t + 2 < NT) stageA(t + 2, 0);
      BARF(); mfma16(1, 0, bfv0); BARF();
      if (t + 2 < NT) stageB(t + 2, 0);
      BARF(); mfma16(1, 1, bfv1);
      if (t + 2 < NT) asm volatile("s_waitcnt vmcnt(4)" ::: "memory");
      else            asm volatile("s_waitcnt vmcnt(0)" ::: "memory");
      BARF();
    }
  } else {
    stageA(0, 0); stageB(0, 0); stageB(0, 1);
    asm volatile("s_waitcnt vmcnt(0)" ::: "memory");
    BARF();
    for (int t = 0; t < NT; ++t) {
      const int buf = t & 1;
      loadA(buf, 0); loadB(buf, 0, bfv0);
      if (t + 1 < NT) { stageA(t + 1, 0); stageB(t + 1, 0); }
      BARF(); mfma16(0, 0, bfv0);
      if (t + 1 < NT) asm volatile("s_waitcnt vmcnt(4)" ::: "memory");
      else            asm volatile("s_waitcnt vmcnt(0)" ::: "memory");
      BARF();
      loadB(buf, 1, bfv1);
      if (t + 1 < NT) stageB(t + 1, 1);
      BARF(); mfma16(0, 1, bfv1);
      if (t + 1 < NT) asm volatile("s_waitcnt vmcnt(2)" ::: "memory");
      BARF();
    }
  }

  constexpr int MFT = (BMT == 256) ? 8 : 4;
  constexpr int WROW = (BMT == 256) ? 128 : 64;
#pragma unroll
  for (int mf = 0; mf < MFT; ++mf)
#pragma unroll
    for (int nf = 0; nf < 4; ++nf) {
      int row = m0 + wm * WROW + mf * 16 + gg * 4;
      int col = n0 + wn * 64 + nf * 16 + c16;
      if (OBF16) {
        u16* cp = Cb + (size_t)row * N + col;
#pragma unroll
        for (int r = 0; r < 4; ++r) cp[(size_t)r * N] = f2bf(acc[mf][nf][r]);
      } else {
        float* cp = C + (size_t)row * N + col;
#pragma unroll
        for (int r = 0; r < 4; ++r) cp[(size_t)r * N] = acc[mf][nf][r];
      }
    }
}

// ---------------- RMSNorm + RoPE + split/cast ----------------
__global__ __launch_bounds__(256) void normrope(const u16* __restrict__ qkv,
                                                const float* __restrict__ freqs,
                                                const float* __restrict__ qw,
                                                const float* __restrict__ kw,
                                                u16* __restrict__ Qb,
                                                u16* __restrict__ Kb,
                                                u16* __restrict__ Vt) {
  int row  = blockIdx.x * 4 + (threadIdx.x >> 6);   // over B*S*24
  int lane = threadIdx.x & 63;
  int bs = row / 24, h = row % 24;
  int b = bs >> 11, s = bs & (S_LEN - 1);
  const u16* src = qkv + (size_t)bs * QKV_E + h * HD;
  ushort2 xr = *(const ushort2*)(src + 2 * lane);
  float x0 = bf2f(xr.x), x1 = bf2f(xr.y);

  float ss = x0 * x0 + x1 * x1;
#pragma unroll
  for (int off = 32; off; off >>= 1) ss += __shfl_xor(ss, off);
  float rn = rsqrtf(ss * (1.0f / 128.0f) + 1e-5f);

  const float scale = 0.08838834764831845f;  // 1/sqrt(128), folded into Q
  if (h < 20) {
    const float* w = (h < 16) ? qw : kw;
    float y0 = x0 * rn * w[2 * lane];
    float y1 = x1 * rn * w[2 * lane + 1];
    float2 f = *(const float2*)(freqs + (size_t)s * 128 + 2 * lane);  // cos, sin
    float r0 = y0 * f.x - y1 * f.y;
    float r1 = y1 * f.x + y0 * f.y;
    ushort2 o;
    if (h < 16) { o.x = f2bf(r0 * scale); o.y = f2bf(r1 * scale); }
    else        { o.x = f2bf(r0);         o.y = f2bf(r1); }
    u16* dst = (h < 16) ? (Qb + ((size_t)(b * NH  + h)      * S_LEN + s) * HD)
                        : (Kb + ((size_t)(b * NKV + h - 16) * S_LEN + s) * HD);
    *(ushort2*)(dst + 2 * lane) = o;
  } else {
    u16* dst = Vt + (size_t)(b * NKV + (h - 20)) * HD * S_LEN;
    dst[(size_t)(2 * lane)     * S_LEN + s] = f2bf(x0);
    dst[(size_t)(2 * lane + 1) * S_LEN + s] = f2bf(x1);
  }
}

// ---------------- MFMA flash attention, 32x32x16, fixed-base softmax ------
// One 128-row q-tile per block (4 waves x 32 q-rows); LPT dispatch order
// (qt = 15 - bx so biggest blocks launch first); 512 blocks = 2/CU (64KB LDS).
// Double-buffered K/V staging, counted vmcnt(8); swapped QK^T; in-register
// P redistribution (cvt_pk + permlane32_swap); L via ones-MFMA.
#define KT 64

__global__ __launch_bounds__(256, 2) void attn_mfma(const u16* __restrict__ Qb,
                                                    const u16* __restrict__ Kb,
                                                    const u16* __restrict__ Vt,
                                                    u16* __restrict__ Yb) {
  __shared__ u16 Ks[2][KT * HD];       // 2 x 16 KB
  __shared__ u16 VtS[2][HD * KT];      // 2 x 16 KB

  const int wid  = threadIdx.x >> 6;
  const int lane = threadIdx.x & 63;
  const int gg   = lane >> 4;          // staging
  const int c16  = lane & 15;          // staging
  const int c31  = lane & 31;
  const int hi   = lane >> 5;
  const int b = blockIdx.z, h = blockIdx.y;
  const int qt = 15 - blockIdx.x;      // LPT: largest tiles dispatched first
  const int hv = h >> 2;

  const u16* Qp = Qb + ((size_t)(b * NH  + h)  * S_LEN) * HD;
  const u16* Kp = Kb + ((size_t)(b * NKV + hv) * S_LEN) * HD;
  const u16* Vp = Vt + ((size_t)(b * NKV + hv) * HD) * S_LEN;

  short8 onesf;
#pragma unroll
  for (int i = 0; i < 8; ++i) onesf[i] = (short)0x3F80;  // bf16 1.0

  auto stageK = [&](int k0, int sel) {
#pragma unroll
    for (int i = 0; i < 4; ++i) {
      int rbase = wid * 16 + i * 4;
      int r = rbase + gg;
      int cb = c16 * 16;
      gload16((const char*)Kp + (size_t)(k0 + r) * 256 + (cb ^ ((r & 7) << 4)),
              (char*)Ks[sel] + rbase * 256);
    }
  };
  auto stageV = [&](int k0, int sel) {
#pragma unroll
    for (int i = 0; i < 4; ++i) {
      int rbase = wid * 32 + i * 8;
      int r = rbase + (lane >> 3);
      int cb = (lane & 7) * 16;
      gload16((const char*)Vp + (size_t)r * (S_LEN * 2) + (size_t)k0 * 2 + (cb ^ ((r & 7) << 4)),
              (char*)VtS[sel] + rbase * 128);
    }
  };

  const int q0  = qt * 128;
  const int q0w = q0 + wid * 32;     // wave's first q row
  const int q   = q0w + c31;         // this lane's q (as S^T column)
  const int nst = 2 * qt + 2;

  // Q fragments (B operand): lane holds Q[q][ds*16 + hi*8 .. +7]
  short8 qf[8];
  {
    const u16* qrow = Qp + (size_t)q * HD + hi * 8;
#pragma unroll
    for (int ds = 0; ds < 8; ++ds) qf[ds] = *(const short8*)(qrow + ds * 16);
  }

  floatx16 Oacc[4] = {};
  floatx16 Lacc = {};

  stageK(0, 0); stageV(0, 0);
  for (int t = 0; t < nst; ++t) {
    const int k0 = t * KT;
    if (t + 1 < nst) { stageK(k0 + KT, (t + 1) & 1); stageV(k0 + KT, (t + 1) & 1); }
    if (t + 1 < nst) asm volatile("s_waitcnt vmcnt(8)" ::: "memory");
    else             asm volatile("s_waitcnt vmcnt(0)" ::: "memory");
    BARF();

    if (k0 <= q0w + 31) {
      const char* KsB = (const char*)Ks[t & 1];
      const char* VtB = (const char*)VtS[t & 1];
      const bool upper = (k0 + 32 <= q0w + 31);   // keys k0+32..k0+63 needed
      const bool fullT = (k0 + 63 <= q0w);        // no masking anywhere

#pragma unroll
      for (int kh = 0; kh < 2; ++kh) {
        if (kh == 1 && !upper) break;
        // ---- QK^T: st = S^T 32k x 32q
        floatx16 st = {};
        const int krow = kh * 32 + c31;
        const char* kbase = KsB + krow * 256;
        const int swz = (krow & 7) << 4;
        __builtin_amdgcn_s_setprio(1);
#pragma unroll
        for (int ds = 0; ds < 8; ++ds) {
          short8 kf = *(const short8*)(kbase + ((ds * 32 + hi * 16) ^ swz));
          st = __builtin_amdgcn_mfma_f32_32x32x16_bf16(kf, qf[ds], st, 0, 0, 0);
        }
        __builtin_amdgcn_s_setprio(0);
        FENCE();
        // ---- p = exp(s), mask; lane's k = kb + (r&3)+8*(r>>2)+4*hi
        const int kb = k0 + kh * 32;
        float p[16];
        if (fullT) {
#pragma unroll
          for (int r = 0; r < 16; ++r) p[r] = __expf(st[r]);
        } else {
#pragma unroll
          for (int r = 0; r < 16; ++r) {
            int k = kb + (r & 3) + 8 * (r >> 2) + 4 * hi;
            p[r] = (k <= q) ? __expf(st[r]) : 0.f;
          }
        }
        // ---- pack to bf16 pairs + permlane32_swap -> PV A-fragments
        unsigned w[8];
#pragma unroll
        for (int m = 0; m < 8; ++m)
          asm("v_cvt_pk_bf16_f32 %0, %1, %2" : "=v"(w[m]) : "v"(p[2*m]), "v"(p[2*m+1]));
        asm volatile("v_permlane32_swap_b32 %0, %1" : "+v"(w[0]), "+v"(w[2]));
        asm volatile("v_permlane32_swap_b32 %0, %1" : "+v"(w[1]), "+v"(w[3]));
        asm volatile("v_permlane32_swap_b32 %0, %1" : "+v"(w[4]), "+v"(w[6]));
        asm volatile("v_permlane32_swap_b32 %0, %1" : "+v"(w[5]), "+v"(w[7]));
        short8 pa0, pa1;
        {
          unsigned u0[4] = {w[0], w[1], w[2], w[3]};
          unsigned u1[4] = {w[4], w[5], w[6], w[7]};
          pa0 = *(const short8*)u0;
          pa1 = *(const short8*)u1;
        }
        // ---- L row-sums + PV
        __builtin_amdgcn_s_setprio(1);
        Lacc = __builtin_amdgcn_mfma_f32_32x32x16_bf16(pa0, onesf, Lacc, 0, 0, 0);
        Lacc = __builtin_amdgcn_mfma_f32_32x32x16_bf16(pa1, onesf, Lacc, 0, 0, 0);
#pragma unroll
        for (int dt = 0; dt < 4; ++dt) {
          const int vr = dt * 32 + c31;
          const char* vbase = VtB + vr * 128;
          const int swzv = (vr & 7) << 4;
          short8 vf0 = *(const short8*)(vbase + (((kh * 2 + 0) * 32 + hi * 16) ^ swzv));
          short8 vf1 = *(const short8*)(vbase + (((kh * 2 + 1) * 32 + hi * 16) ^ swzv));
          Oacc[dt] = __builtin_amdgcn_mfma_f32_32x32x16_bf16(pa0, vf0, Oacc[dt], 0, 0, 0);
          Oacc[dt] = __builtin_amdgcn_mfma_f32_32x32x16_bf16(pa1, vf1, Oacc[dt], 0, 0, 0);
        }
        __builtin_amdgcn_s_setprio(0);
        FENCE();
      }
    }
    BARF();
  }

  // ---- epilogue: O / L -> Yb [b][s][h*128+d]; row q = (r&3)+8*(r>>2)+4*hi
  float linv[16];
#pragma unroll
  for (int r = 0; r < 16; ++r) linv[r] = 1.0f / Lacc[r];
#pragma unroll
  for (int dt = 0; dt < 4; ++dt) {
    const int d = dt * 32 + c31;
#pragma unroll
    for (int r = 0; r < 16; ++r) {
      int qg = q0w + (r & 3) + 8 * (r >> 2) + 4 * hi;
      Yb[((size_t)(b * S_LEN + qg)) * DIM + h * HD + d] = f2bf(Oacc[dt][r] * linv[r]);
    }
  }
}

// ---------------- launch ----------------
extern "C" void kernel_launch(void* const* d_in, const int* in_sizes, int n_in,
                              void* d_out, int out_size, void* d_ws, size_t ws_size,
                              hipStream_t stream) {
  const float* x     = (const float*)d_in[0];
  const float* freqs = (const float*)d_in[1];
  const float* wqkv  = (const float*)d_in[3];
  const float* wo    = (const float*)d_in[4];
  const float* qw    = (const float*)d_in[5];
  const float* kw    = (const float*)d_in[6];
  float* out = (float*)d_out;
  char* ws = (char*)d_ws;

  const int M = 2 * S_LEN;  // 4096 rows (B*S)

  u16* xb    = (u16*)(ws);                 // 16 MB
  u16* wqkvb = (u16*)(ws + 16777216);      // 12 MB
  u16* wob   = (u16*)(ws + 29360128);      //  8 MB
  u16* qkvb  = (u16*)(ws + 37748736);      // 24 MB (bf16 GEMM output)
  u16* Qb    = (u16*)(ws + 62914560);      // 16 MB
  u16* Kb    = (u16*)(ws + 79691776);      //  4 MB
  u16* Vt    = (u16*)(ws + 83886080);      //  4 MB
  u16* Yb    = (u16*)(ws + 88080384);      // 16 MB  (end 100 MB)

  hipFuncSetAttribute((const void*)gemm256<1, 256>,
                      hipFuncAttributeMaxDynamicSharedMemorySize, 131072);
  hipFuncSetAttribute((const void*)gemm256<0, 128>,
                      hipFuncAttributeMaxDynamicSharedMemorySize, 98304);

  cast3<<<2048, 256, 0, stream>>>(x, wqkv, wo, xb, wqkvb, wob);

  gemm256<1, 256><<<dim3(QKV_E / 256, M / 256), 512, 131072, stream>>>(
      xb, wqkvb, nullptr, qkvb, M, QKV_E, DIM);

  normrope<<<(M * 24) / 4, 256, 0, stream>>>(qkvb, freqs, qw, kw, Qb, Kb, Vt);

  attn_mfma<<<dim3(16, NH, 2), 256, 0, stream>>>(Qb, Kb, Vt, Yb);

  gemm256<0, 128><<<dim3(DIM / 256, M / 128), 512, 98304, stream>>>(
      Yb, wob, out, nullptr, M, DIM, DIM);
}